// Round 2
// 229.932 us; speedup vs baseline: 1.1083x; 1.1083x over previous
//
#include <hip/hip_runtime.h>
#include <cstdint>

#define N_IMG 32
#define C_IN 128
#define H_IN 56
#define W_IN 56
#define K_OUT 256
#define HW (H_IN * W_IN)            // 3136
#define M_TOTAL (N_IMG * HW)        // 100352
#define XP_H 58
#define XP_W 58
#define XP_ELEMS (N_IMG * XP_H * XP_W * C_IN)   // 13,778,944 bf16
#define WT_ELEMS (9 * K_OUT * C_IN)             // 294,912 bf16
#define NKT 18                      // K-tiles of 64: 9 rs positions x 2 c-halves

typedef __bf16 bf16x8 __attribute__((ext_vector_type(8)));
typedef float f32x4 __attribute__((ext_vector_type(4)));

__device__ __align__(16) unsigned short g_xp[XP_ELEMS];  // padded NHWC bf16 input
__device__ __align__(16) unsigned short g_wt[WT_ELEMS];  // wt[rs][k][c] bf16 weights

static __device__ __forceinline__ unsigned short f2bf(float f) {
    unsigned int u = __builtin_bit_cast(unsigned int, f);
    u += 0x7fffu + ((u >> 16) & 1u);   // RNE
    return (unsigned short)(u >> 16);
}

// async global->LDS, 16 bytes per lane; LDS dest = wave-uniform base + lane*16
static __device__ __forceinline__ void async_copy16(const unsigned short* g, unsigned short* l) {
    auto gp = (const __attribute__((address_space(1))) unsigned int*)g;
    auto lp = (__attribute__((address_space(3))) unsigned int*)l;
    __builtin_amdgcn_global_load_lds(gp, lp, 16, 0, 0);
}

// ---------------- prep kernel 1: NCHW fp32 -> padded NHWC bf16 (+border zero) --
__global__ __launch_bounds__(256) void xpose_x(const float* __restrict__ x) {
    __shared__ float tile[C_IN * 57];     // [c][w] padded
    const int h = blockIdx.x;
    const int n = blockIdx.y;
    const int tid = threadIdx.x;

    if (tid < 32) {
        int col = (tid >> 4) * (XP_W - 1);          // 0 or 57
        int q = tid & 15;
        uint4* dst = (uint4*)(g_xp + ((size_t)(n * XP_H + h + 1) * XP_W + col) * C_IN) + q;
        *dst = uint4{0u, 0u, 0u, 0u};
    }
    if (h == 0 || h == H_IN - 1) {
        int hp = (h == 0) ? 0 : XP_H - 1;
        uint4* base = (uint4*)(g_xp + ((size_t)(n * XP_H + hp) * XP_W) * C_IN);
        for (int q = tid; q < (XP_W * C_IN) / 8; q += 256) base[q] = uint4{0u, 0u, 0u, 0u};
    }

#pragma unroll
    for (int i = 0; i < 28; i++) {
        int e = i * 256 + tid;
        int c = e / 56;
        int w = e - c * 56;
        tile[c * 57 + w] = x[((n * C_IN + c) * H_IN + h) * W_IN + w];
    }
    __syncthreads();
    unsigned int* outp = (unsigned int*)g_xp;
#pragma unroll
    for (int i = 0; i < 14; i++) {
        int u = i * 256 + tid;
        int w = u >> 6;
        int cp = u & 63;
        float a = tile[(2 * cp) * 57 + w];
        float b = tile[(2 * cp + 1) * 57 + w];
        unsigned int pk = (unsigned int)f2bf(a) | ((unsigned int)f2bf(b) << 16);
        int idx = ((n * XP_H + h + 1) * XP_W + (w + 1)) * C_IN + 2 * cp;
        outp[idx >> 1] = pk;
    }
}

// ---------------- prep kernel 2: OIHW fp32 -> wt[rs][k][c] bf16 ----------------
__global__ __launch_bounds__(256) void xpose_w(const float* __restrict__ w) {
    int e = blockIdx.x * 256 + threadIdx.x;
    int rr = e >> 15;
    int rem = e & 32767;
    int k = rem >> 7;
    int c = rem & 127;
    g_wt[e] = f2bf(w[(k * C_IN + c) * 9 + rr]);
}

// ---------------- main: implicit-GEMM, 256x256 tile, BK=64, 8 waves ------------
// 4 phases/K-tile; WHOLE-TILE vmcnt ledger with 2-tile lookahead (race fix from
// round 1: every wave reads both A-halves and both B-halves starting at P1, so
// the full tile must be LDS-resident before the iteration's first ds_read).
//   prologue: stage t0->buf0, t1->buf1; vmcnt(8) (t0 landed); barrier
//   iter t:   P1..P3 read buf b=t&1 (no vmcnt); end-of-P3 barrier proves all
//             waves done reading b; P4 stages t+2 -> b, MFMA, vmcnt(8) retires
//             t+1 (issued 4 phases earlier, wait~0), barrier.
// Loads stay in flight across every barrier (never drains to 0 in the loop).
// T2 XOR-swizzle via pre-swizzled global source + swizzled ds_read (rule 21).
__global__ __launch_bounds__(512, 2) void conv_main(float* __restrict__ out) {
    __shared__ __align__(16) unsigned short As[2][16384];   // [buf][256 rows x 64]
    __shared__ __align__(16) unsigned short Bs[2][16384];
    const unsigned short* __restrict__ xp = g_xp;
    const unsigned short* __restrict__ wt = g_wt;

    const int tid = threadIdx.x;
    const int wave = tid >> 6, lane = tid & 63;
    const int lr = lane & 15, lq = lane >> 4;
    const int wr = wave >> 2;       // 0..1 : M half (128 rows)
    const int wc = wave & 3;        // 0..3 : N quarter (64 cols)

    // XCD-aware bijective swizzle: 392 blocks = 8 XCDs x 49 contiguous tiles
    const int bid = blockIdx.x;
    const int m0 = ((bid & 7) * 49 + (bid >> 3)) * 256;

    // staging constants: unit u = j*512+tid -> rowl=u>>3 (0..127), seg=u&7.
    // source column PRE-SWIZZLED (seg ^ rowl&7) so linear global_load_lds dest
    // + swizzled ds_read form the same involution.
    int a_src[2][2], b_src[2][2], lds_u[2];
#pragma unroll
    for (int j = 0; j < 2; j++) {
        const int u = j * 512 + tid;
        const int rowl = u >> 3;
        const int sw = ((u & 7) ^ (rowl & 7)) * 8;
        lds_u[j] = (j * 512 + wave * 64) * 8;    // wave-uniform; HW adds lane*16B
#pragma unroll
        for (int hh = 0; hh < 2; hh++) {
            int p = m0 + hh * 128 + rowl;
            int n = p / HW;
            int rem = p - n * HW;
            int h = rem / W_IN;
            int w = rem - h * W_IN;
            a_src[j][hh] = ((n * XP_H + h) * XP_W + w) * C_IN + sw;
            b_src[j][hh] = (hh * 128 + rowl) * C_IN + sw;
        }
    }

    // ds_read lane constants: swizzled column (shorts) per k-step
    int csw[2];
#pragma unroll
    for (int ks = 0; ks < 2; ks++)
        csw[ks] = (ks * 32 + lq * 8) ^ ((lr & 7) << 3);
    const int arow = (wr * 128 + lr) * 64;
    const int brow = (wc * 64 + lr) * 64;

    // stage a FULL K-tile kt into buffer nb: 8 global_load_lds units per thread
    auto stage_tile = [&](int kt, int nb) {
        const int rs = kt >> 1;
        const int r = (rs * 11) >> 5;            // rs/3
        const int sc = rs - r * 3;               // rs%3
        const int aoff = (r * XP_W + sc) * C_IN + (kt & 1) * 64;
        const int boff = rs * (K_OUT * C_IN) + (kt & 1) * 64;
#pragma unroll
        for (int hh = 0; hh < 2; hh++)
#pragma unroll
            for (int j = 0; j < 2; j++) {
                async_copy16(xp + a_src[j][hh] + aoff, &As[nb][hh * 8192 + lds_u[j]]);
                async_copy16(wt + b_src[j][hh] + boff, &Bs[nb][hh * 8192 + lds_u[j]]);
            }
    };

    f32x4 acc[8][4];
#pragma unroll
    for (int mi = 0; mi < 8; mi++)
#pragma unroll
        for (int ni = 0; ni < 4; ni++) acc[mi][ni] = f32x4{0.f, 0.f, 0.f, 0.f};

    // prologue: tile0 -> buf0, tile1 -> buf1; wait tile0 only
    stage_tile(0, 0);
    stage_tile(1, 1);
    asm volatile("s_waitcnt vmcnt(8)" ::: "memory");
    __builtin_amdgcn_s_barrier();
    asm volatile("" ::: "memory");

    for (int t = 0; t < NKT - 1; ++t) {
        const int b = t & 1;
        bf16x8 a0[4][2], bL[2][2], bH[2][2], a1[4][2];

        // ---- P1: (m-lo, n-lo) quadrant of this wave's 128x64 block ----
#pragma unroll
        for (int mi = 0; mi < 4; mi++)
#pragma unroll
            for (int ks = 0; ks < 2; ks++)
                a0[mi][ks] = *(const bf16x8*)(&As[b][arow + mi * 1024 + csw[ks]]);
#pragma unroll
        for (int ni = 0; ni < 2; ni++)
#pragma unroll
            for (int ks = 0; ks < 2; ks++)
                bL[ni][ks] = *(const bf16x8*)(&Bs[b][brow + ni * 1024 + csw[ks]]);
        __builtin_amdgcn_s_barrier();
        asm volatile("s_waitcnt lgkmcnt(0)" ::: "memory");
        __builtin_amdgcn_s_setprio(1);
#pragma unroll
        for (int ks = 0; ks < 2; ks++)
#pragma unroll
            for (int mi = 0; mi < 4; mi++)
#pragma unroll
                for (int ni = 0; ni < 2; ni++)
                    acc[mi][ni] = __builtin_amdgcn_mfma_f32_16x16x32_bf16(
                        a0[mi][ks], bL[ni][ks], acc[mi][ni], 0, 0, 0);
        __builtin_amdgcn_s_setprio(0);
        __builtin_amdgcn_s_barrier();
        asm volatile("" ::: "memory");

        // ---- P2: (m-lo, n-hi) ----
#pragma unroll
        for (int ni = 0; ni < 2; ni++)
#pragma unroll
            for (int ks = 0; ks < 2; ks++)
                bH[ni][ks] = *(const bf16x8*)(&Bs[b][brow + (ni + 2) * 1024 + csw[ks]]);
        __builtin_amdgcn_s_barrier();
        asm volatile("s_waitcnt lgkmcnt(0)" ::: "memory");
        __builtin_amdgcn_s_setprio(1);
#pragma unroll
        for (int ks = 0; ks < 2; ks++)
#pragma unroll
            for (int mi = 0; mi < 4; mi++)
#pragma unroll
                for (int ni = 0; ni < 2; ni++)
                    acc[mi][ni + 2] = __builtin_amdgcn_mfma_f32_16x16x32_bf16(
                        a0[mi][ks], bH[ni][ks], acc[mi][ni + 2], 0, 0, 0);
        __builtin_amdgcn_s_setprio(0);
        __builtin_amdgcn_s_barrier();
        asm volatile("" ::: "memory");

        // ---- P3: (m-hi, n-hi) ----
#pragma unroll
        for (int mi = 0; mi < 4; mi++)
#pragma unroll
            for (int ks = 0; ks < 2; ks++)
                a1[mi][ks] = *(const bf16x8*)(&As[b][arow + (mi + 4) * 1024 + csw[ks]]);
        __builtin_amdgcn_s_barrier();
        asm volatile("s_waitcnt lgkmcnt(0)" ::: "memory");
        __builtin_amdgcn_s_setprio(1);
#pragma unroll
        for (int ks = 0; ks < 2; ks++)
#pragma unroll
            for (int mi = 0; mi < 4; mi++)
#pragma unroll
                for (int ni = 0; ni < 2; ni++)
                    acc[mi + 4][ni + 2] = __builtin_amdgcn_mfma_f32_16x16x32_bf16(
                        a1[mi][ks], bH[ni][ks], acc[mi + 4][ni + 2], 0, 0, 0);
        __builtin_amdgcn_s_setprio(0);
        __builtin_amdgcn_s_barrier();
        asm volatile("" ::: "memory");
        // end-of-P3 barrier: ALL waves have finished their ds_reads of buf b
        // (each wave's lgkmcnt(0) preceded this barrier) -> safe to overwrite b.

        // ---- P4: (m-hi, n-lo); stage tile t+2 into buf b ----
        if (t + 2 < NKT) stage_tile(t + 2, b);
        __builtin_amdgcn_s_setprio(1);
#pragma unroll
        for (int ks = 0; ks < 2; ks++)
#pragma unroll
            for (int mi = 0; mi < 4; mi++)
#pragma unroll
                for (int ni = 0; ni < 2; ni++)
                    acc[mi + 4][ni] = __builtin_amdgcn_mfma_f32_16x16x32_bf16(
                        a1[mi][ks], bL[ni][ks], acc[mi + 4][ni], 0, 0, 0);
        __builtin_amdgcn_s_setprio(0);
        // retire tile t+1 (8 units, issued ~4 phases ago); keep t+2 in flight
        if (t + 2 < NKT) {
            asm volatile("s_waitcnt vmcnt(8)" ::: "memory");
        } else {
            asm volatile("s_waitcnt vmcnt(0)" ::: "memory");
        }
        __builtin_amdgcn_s_barrier();
        asm volatile("" ::: "memory");
    }

    // tail K-tile 17 (buf 1): fully resident; compute in 2 halves
    {
        constexpr int b = 1;
        bf16x8 af[4][2], bb[4][2];
#pragma unroll
        for (int ni = 0; ni < 4; ni++)
#pragma unroll
            for (int ks = 0; ks < 2; ks++)
                bb[ni][ks] = *(const bf16x8*)(&Bs[b][brow + ni * 1024 + csw[ks]]);
#pragma unroll
        for (int mi = 0; mi < 4; mi++)
#pragma unroll
            for (int ks = 0; ks < 2; ks++)
                af[mi][ks] = *(const bf16x8*)(&As[b][arow + mi * 1024 + csw[ks]]);
#pragma unroll
        for (int ks = 0; ks < 2; ks++)
#pragma unroll
            for (int mi = 0; mi < 4; mi++)
#pragma unroll
                for (int ni = 0; ni < 4; ni++)
                    acc[mi][ni] = __builtin_amdgcn_mfma_f32_16x16x32_bf16(
                        af[mi][ks], bb[ni][ks], acc[mi][ni], 0, 0, 0);
#pragma unroll
        for (int mi = 0; mi < 4; mi++)
#pragma unroll
            for (int ks = 0; ks < 2; ks++)
                af[mi][ks] = *(const bf16x8*)(&As[b][arow + (mi + 4) * 1024 + csw[ks]]);
#pragma unroll
        for (int ks = 0; ks < 2; ks++)
#pragma unroll
            for (int mi = 0; mi < 4; mi++)
#pragma unroll
                for (int ni = 0; ni < 4; ni++)
                    acc[mi + 4][ni] = __builtin_amdgcn_mfma_f32_16x16x32_bf16(
                        af[mi][ks], bb[ni][ks], acc[mi + 4][ni], 0, 0, 0);
    }

    // epilogue: lane's float4 = 4 consecutive pixels at fixed out-channel k
#pragma unroll
    for (int mi = 0; mi < 8; mi++) {
        int p = m0 + wr * 128 + mi * 16 + lq * 4;   // mult of 4; 3136%4==0
        int n = p / HW;
        int off = p - n * HW;
#pragma unroll
        for (int ni = 0; ni < 4; ni++) {
            int k = wc * 64 + ni * 16 + lr;
            *(f32x4*)(out + (n * K_OUT + k) * HW + off) = acc[mi][ni];
        }
    }
}

extern "C" void kernel_launch(void* const* d_in, const int* in_sizes, int n_in,
                              void* d_out, int out_size, void* d_ws, size_t ws_size,
                              hipStream_t stream) {
    const float* x = (const float*)d_in[0];
    const float* w = (const float*)d_in[1];
    float* out = (float*)d_out;

    hipLaunchKernelGGL(xpose_x, dim3(H_IN, N_IMG), dim3(256), 0, stream, x);
    hipLaunchKernelGGL(xpose_w, dim3(WT_ELEMS / 256), dim3(256), 0, stream, w);
    hipLaunchKernelGGL(conv_main, dim3(M_TOTAL / 256), dim3(512), 0, stream, out);
}